// Round 1
// baseline (165.980 us; speedup 1.0000x reference)
//
#include <hip/hip_runtime.h>

#define NB   512
#define NN   32
#define OBSD 128
#define NAD  16
#define OAD  144
#define DD   64

// LDS float offsets (total 24928 floats = 99712 B)
#define WB_OFF   0        // W^T buffer: up to 144 rows x stride 68
#define S_OFF    9792     // states 32x132 (4224 f) / later EA,EP 2x32x68 (4352 f)
#define E_OFF    14144    // embed 32x68 / later NF
#define KQ_OFF   16320    // K,Q 2x32x68 / later AA,AP
#define SP_OFF   20672    // SP 32x68 / later H
#define WT_OFF   22848    // score/weight 32x33
#define ACT_OFF  23904    // 32x16
#define POL_OFF  24416    // 32x16
#define LDS_TOT  24928

__device__ __forceinline__ void fma4(float4& a, float s, float4 w) {
    a.x = fmaf(s, w.x, a.x);
    a.y = fmaf(s, w.y, a.y);
    a.z = fmaf(s, w.z, a.z);
    a.w = fmaf(s, w.w, a.w);
}

// acc += s4 (4 consecutive k) against W^T rows k..k+3 at wbase = Wb + k*68 + o4*4
#define MV_STEP(acc, s4, wbase)                                   \
    fma4(acc, (s4).x, *(const float4*)((wbase)));                 \
    fma4(acc, (s4).y, *(const float4*)((wbase) + 68));            \
    fma4(acc, (s4).z, *(const float4*)((wbase) + 136));           \
    fma4(acc, (s4).w, *(const float4*)((wbase) + 204));

__global__ void __launch_bounds__(512)
critic_fused(const float* __restrict__ states,
             const float* __restrict__ policies,
             const float* __restrict__ actions,
             const float* __restrict__ W_obs, const float* __restrict__ b_obs,
             const float* __restrict__ W_oa,  const float* __restrict__ b_oa,
             const float* __restrict__ W_key, const float* __restrict__ W_query,
             const float* __restrict__ W_av,  const float* __restrict__ W_f1,
             const float* __restrict__ W_f2,
             float* __restrict__ out_value,   // [B,N,16]
             float* __restrict__ out_weight)  // [B,N,N]
{
    __shared__ float lds[LDS_TOT];
    const int b = blockIdx.x;
    const int t = threadIdx.x;
    const int i_ag = t >> 4;   // 0..31 (agent / row)
    const int o4   = t & 15;   // 0..15 (float4 block of 64-wide output)

    float* Wb  = lds + WB_OFF;
    float* S   = lds + S_OFF;
    float* E   = lds + E_OFF;
    float* KQ  = lds + KQ_OFF;
    float* SP  = lds + SP_OFF;
    float* Wt  = lds + WT_OFF;
    float* ACT = lds + ACT_OFF;
    float* POL = lds + POL_OFF;

    // ---------- phase 1: load states / act / pol, stage W_obs^T ----------
    {
        const float4* src = (const float4*)(states + (size_t)b * NN * OBSD);
        #pragma unroll
        for (int rep = 0; rep < 2; ++rep) {
            int e = t + rep * 512;          // 1024 float4 total
            int i = e >> 5, j = e & 31;
            float4 v = src[e];
            *(float4*)(S + i * 132 + j * 4) = v;
        }
        ACT[t] = actions[(size_t)b * NN * NAD + t];
        POL[t] = policies[(size_t)b * NN * NAD + t];
        #pragma unroll
        for (int rep = 0; rep < 16; ++rep) {  // 64x128 = 8192
            int e = t + rep * 512;
            int o = e >> 7, k = e & 127;
            Wb[k * 68 + o] = W_obs[e];
        }
    }
    __syncthreads();

    // ---------- phase 2: E = relu(states @ W_obs^T + b_obs) ----------
    {
        float4 acc = *(const float4*)(b_obs + o4 * 4);
        const float* srow = S + i_ag * 132;
        for (int k = 0; k < 128; k += 4) {
            float4 s4 = *(const float4*)(srow + k);
            const float* wb = Wb + k * 68 + o4 * 4;
            MV_STEP(acc, s4, wb);
        }
        acc.x = fmaxf(acc.x, 0.f); acc.y = fmaxf(acc.y, 0.f);
        acc.z = fmaxf(acc.z, 0.f); acc.w = fmaxf(acc.w, 0.f);
        *(float4*)(E + i_ag * 68 + o4 * 4) = acc;
    }
    __syncthreads();

    // ---------- stage W_key (rows 0..63), W_query (rows 64..127) ----------
    {
        #pragma unroll
        for (int rep = 0; rep < 8; ++rep) {
            int e = t + rep * 512; int o = e >> 6, k = e & 63;
            Wb[k * 68 + o] = W_key[e];
        }
        #pragma unroll
        for (int rep = 0; rep < 8; ++rep) {
            int e = t + rep * 512; int o = e >> 6, k = e & 63;
            Wb[(64 + k) * 68 + o] = W_query[e];
        }
    }
    __syncthreads();

    // ---------- phase 3: K = E @ W_key^T, Q = E @ W_query^T ----------
    {
        float4 ak = make_float4(0.f, 0.f, 0.f, 0.f);
        float4 aq = make_float4(0.f, 0.f, 0.f, 0.f);
        const float* erow = E + i_ag * 68;
        for (int k = 0; k < 64; k += 4) {
            float4 e4 = *(const float4*)(erow + k);
            const float* wk = Wb + k * 68 + o4 * 4;
            const float* wq = Wb + (64 + k) * 68 + o4 * 4;
            MV_STEP(ak, e4, wk);
            MV_STEP(aq, e4, wq);
        }
        *(float4*)(KQ + i_ag * 68 + o4 * 4) = ak;
        *(float4*)(KQ + (32 + i_ag) * 68 + o4 * 4) = aq;
    }
    __syncthreads();

    // ---------- score (raw -> Wt) + stage W_oa^T (144 rows) ----------
    {
        int j  = t & 31;
        int ia = (t >> 5) * 2;
        const float* Kj = KQ + j * 68;
        const float* Qa = KQ + (32 + ia) * 68;
        const float* Qb = Qa + 68;
        float sa = 0.f, sb = 0.f;
        for (int d = 0; d < 64; d += 4) {
            float4 k4 = *(const float4*)(Kj + d);
            float4 qa = *(const float4*)(Qa + d);
            float4 qb = *(const float4*)(Qb + d);
            sa += k4.x * qa.x + k4.y * qa.y + k4.z * qa.z + k4.w * qa.w;
            sb += k4.x * qb.x + k4.y * qb.y + k4.z * qb.z + k4.w * qb.w;
        }
        Wt[j * 33 + ia]     = sa * 0.125f;   // /sqrt(64)
        Wt[j * 33 + ia + 1] = sb * 0.125f;
        #pragma unroll
        for (int rep = 0; rep < 18; ++rep) {  // 64x144 = 9216
            int e = t + rep * 512;
            int o = e / 144, k = e - o * 144;
            Wb[k * 68 + o] = W_oa[e];
        }
    }
    __syncthreads();

    // ---------- softmax (rows of Wt) + phase 4: SP = states @ W_oa[:,:128]^T + b_oa ----------
    {
        int j = t >> 4, sub = t & 15;
        float s0 = Wt[j * 33 + sub], s1 = Wt[j * 33 + sub + 16];
        float m = fmaxf(s0, s1);
        #pragma unroll
        for (int off = 8; off > 0; off >>= 1)
            m = fmaxf(m, __shfl_xor(m, off, 16));
        float e0 = __expf(s0 - m), e1 = __expf(s1 - m);
        float ssum = e0 + e1;
        #pragma unroll
        for (int off = 8; off > 0; off >>= 1)
            ssum += __shfl_xor(ssum, off, 16);
        float inv = 1.0f / ssum;
        e0 *= inv; e1 *= inv;
        Wt[j * 33 + sub]      = e0;
        Wt[j * 33 + sub + 16] = e1;
        float* wout = out_weight + (size_t)b * (NN * NN) + j * NN;
        wout[sub]      = e0;
        wout[sub + 16] = e1;
    }
    {
        float4 acc = *(const float4*)(b_oa + o4 * 4);
        const float* srow = S + i_ag * 132;
        for (int k = 0; k < 128; k += 4) {
            float4 s4 = *(const float4*)(srow + k);
            const float* wb = Wb + k * 68 + o4 * 4;
            MV_STEP(acc, s4, wb);
        }
        *(float4*)(SP + i_ag * 68 + o4 * 4) = acc;
    }
    __syncthreads();

    // ---------- phase 5a: EA/EP = relu(SP + tail(act/pol)) -> S slot ----------
    {
        float4 base = *(const float4*)(SP + i_ag * 68 + o4 * 4);
        float4 aA = base, aP = base;
        const float* arow = ACT + i_ag * 16;
        const float* prow = POL + i_ag * 16;
        #pragma unroll
        for (int k = 0; k < 16; k += 4) {
            float4 a4 = *(const float4*)(arow + k);
            float4 p4 = *(const float4*)(prow + k);
            const float* wb = Wb + (128 + k) * 68 + o4 * 4;
            MV_STEP(aA, a4, wb);
            MV_STEP(aP, p4, wb);
        }
        aA.x = fmaxf(aA.x, 0.f); aA.y = fmaxf(aA.y, 0.f);
        aA.z = fmaxf(aA.z, 0.f); aA.w = fmaxf(aA.w, 0.f);
        aP.x = fmaxf(aP.x, 0.f); aP.y = fmaxf(aP.y, 0.f);
        aP.z = fmaxf(aP.z, 0.f); aP.w = fmaxf(aP.w, 0.f);
        *(float4*)(S + i_ag * 68 + o4 * 4)        = aA;  // EA
        *(float4*)(S + (32 + i_ag) * 68 + o4 * 4) = aP;  // EP
    }
    __syncthreads();

    // ---------- stage W_av (rows 0..63), W_f1 (rows 64..127), W_f2 natural (rows 128..143) ----------
    {
        #pragma unroll
        for (int rep = 0; rep < 8; ++rep) {
            int e = t + rep * 512; int o = e >> 6, k = e & 63;
            Wb[k * 68 + o] = W_av[e];
        }
        #pragma unroll
        for (int rep = 0; rep < 8; ++rep) {
            int e = t + rep * 512; int o = e >> 6, k = e & 63;
            Wb[(64 + k) * 68 + o] = W_f1[e];
        }
        #pragma unroll
        for (int rep = 0; rep < 2; ++rep) {
            int e = t + rep * 512; int p = e >> 6, k = e & 63;
            Wb[(128 + p) * 68 + k] = W_f2[e];   // natural layout
        }
    }
    __syncthreads();

    // ---------- phase 5b: AA/AP = tanh(EA/EP @ W_av^T) -> KQ slot ----------
    {
        float4 aA = make_float4(0.f, 0.f, 0.f, 0.f);
        float4 aP = make_float4(0.f, 0.f, 0.f, 0.f);
        const float* ea = S + i_ag * 68;
        const float* ep = S + (32 + i_ag) * 68;
        for (int k = 0; k < 64; k += 4) {
            float4 e4a = *(const float4*)(ea + k);
            float4 e4p = *(const float4*)(ep + k);
            const float* wb = Wb + k * 68 + o4 * 4;
            MV_STEP(aA, e4a, wb);
            MV_STEP(aP, e4p, wb);
        }
        aA.x = tanhf(aA.x); aA.y = tanhf(aA.y); aA.z = tanhf(aA.z); aA.w = tanhf(aA.w);
        aP.x = tanhf(aP.x); aP.y = tanhf(aP.y); aP.z = tanhf(aP.z); aP.w = tanhf(aP.w);
        *(float4*)(KQ + i_ag * 68 + o4 * 4)        = aA;  // AA
        *(float4*)(KQ + (32 + i_ag) * 68 + o4 * 4) = aP;  // AP
    }
    __syncthreads();

    // ---------- phase 6: NF[j] = (1/32)[ sum_i w[j,i]*AA[i] + w[j,j]*(AP[j]-AA[j]) ] -> E slot ----------
    {
        int jr = i_ag;
        float4 acc = make_float4(0.f, 0.f, 0.f, 0.f);
        for (int i = 0; i < 32; ++i) {
            float wgt = Wt[jr * 33 + i];
            float4 av4 = *(const float4*)(KQ + i * 68 + o4 * 4);
            fma4(acc, wgt, av4);
        }
        float wjj = Wt[jr * 33 + jr];
        float4 aaj = *(const float4*)(KQ + jr * 68 + o4 * 4);
        float4 apj = *(const float4*)(KQ + (32 + jr) * 68 + o4 * 4);
        acc.x = (acc.x + wjj * (apj.x - aaj.x)) * (1.0f / 32.0f);
        acc.y = (acc.y + wjj * (apj.y - aaj.y)) * (1.0f / 32.0f);
        acc.z = (acc.z + wjj * (apj.z - aaj.z)) * (1.0f / 32.0f);
        acc.w = (acc.w + wjj * (apj.w - aaj.w)) * (1.0f / 32.0f);
        *(float4*)(E + jr * 68 + o4 * 4) = acc;   // NF
    }
    __syncthreads();

    // ---------- phase 7a: H = leaky_relu(NF @ W_f1^T) -> SP slot ----------
    {
        int jr = i_ag;
        float4 acc = make_float4(0.f, 0.f, 0.f, 0.f);
        const float* nfr = E + jr * 68;
        for (int k = 0; k < 64; k += 4) {
            float4 n4 = *(const float4*)(nfr + k);
            const float* wb = Wb + (64 + k) * 68 + o4 * 4;
            MV_STEP(acc, n4, wb);
        }
        acc.x = fmaxf(acc.x, 0.01f * acc.x);
        acc.y = fmaxf(acc.y, 0.01f * acc.y);
        acc.z = fmaxf(acc.z, 0.01f * acc.z);
        acc.w = fmaxf(acc.w, 0.01f * acc.w);
        *(float4*)(SP + jr * 68 + o4 * 4) = acc;  // H
    }
    __syncthreads();

    // ---------- phase 7b: value = H @ W_f2^T ----------
    {
        int jr = t >> 4, p = t & 15;
        const float* hrow = SP + jr * 68;
        const float* w2r  = Wb + (128 + p) * 68;
        float acc = 0.f;
        for (int k = 0; k < 64; k += 4) {
            float4 h4 = *(const float4*)(hrow + k);
            float4 w4 = *(const float4*)(w2r + k);
            acc += h4.x * w4.x + h4.y * w4.y + h4.z * w4.z + h4.w * w4.w;
        }
        out_value[(size_t)b * (NN * NAD) + t] = acc;  // jr*16+p == t
    }
}

extern "C" void kernel_launch(void* const* d_in, const int* in_sizes, int n_in,
                              void* d_out, int out_size, void* d_ws, size_t ws_size,
                              hipStream_t stream) {
    const float* states   = (const float*)d_in[0];
    const float* policies = (const float*)d_in[1];
    const float* actions  = (const float*)d_in[2];
    const float* W_obs    = (const float*)d_in[3];
    const float* b_obs    = (const float*)d_in[4];
    const float* W_oa     = (const float*)d_in[5];
    const float* b_oa     = (const float*)d_in[6];
    const float* W_key    = (const float*)d_in[7];
    const float* W_query  = (const float*)d_in[8];
    const float* W_av     = (const float*)d_in[9];
    const float* W_f1     = (const float*)d_in[10];
    const float* W_f2     = (const float*)d_in[11];

    float* out_value  = (float*)d_out;                       // [512,32,16]
    float* out_weight = (float*)d_out + NB * NN * NAD;       // [512,32,32]

    critic_fused<<<NB, 512, 0, stream>>>(states, policies, actions,
                                         W_obs, b_obs, W_oa, b_oa,
                                         W_key, W_query, W_av, W_f1, W_f2,
                                         out_value, out_weight);
}

// Round 2
// 50.649 us; speedup vs baseline: 3.2771x; 3.2771x over previous
//
#include <hip/hip_runtime.h>

#define NB 512

// ---- d_ws layout (floats): transposed weights W^T[k][o] ----
#define WOBS_T 0        // [128][64]
#define WOA_T  8192     // [144][64]
#define WK_T   17408    // [64][64]
#define WQ_T   21504    // [64][64]
#define WAV_T  25600    // [64][64]
#define WF1_T  29696    // [64][64]
#define WF2_T  33792    // [64][16]
#define WS_FLOATS 34816 // 139264 bytes

// ---- LDS arena (floats), total 12288 = 48 KiB ----
// R1 [4096]: S_T[128][32] -> K_T[64][32]@R1, Q_T@R1+2048 -> AA[32][64]@R1, AP@R1+2048 -> H_T[64][32]@R1
// R2 [5120]: AT[16][32]@R2, PT@R2+512, EA_T[64][32]@R2+1024, EP_T@R2+3072
// R3 [2048]: E_T[64][32] -> NF_T[64][32]
// R4 [1024]: WT[32][32] (attention weights, transposed: WT[i][j] = w[j][i])
#define R1 0
#define R2 4096
#define R3 9216
#define R4 11264
#define LDSF 12288

// swizzled [row][32-agent] addressing: agent-quad XOR'd with (row>>2)&7
__device__ __forceinline__ int tq(int r, int q) {
    return r * 32 + (((q ^ (r >> 2)) & 7) << 2);
}
__device__ __forceinline__ int ta(int r, int a) {
    return tq(r, a >> 2) + (a & 3);
}

__device__ __forceinline__ void fma4(float4& a, float s, float4 w) {
    a.x = fmaf(s, w.x, a.x);
    a.y = fmaf(s, w.y, a.y);
    a.z = fmaf(s, w.z, a.z);
    a.w = fmaf(s, w.w, a.w);
}

#define FMA_QUAD(acc, s4, w4)                 \
    fma4(acc[0], (s4).x, (w4));               \
    fma4(acc[1], (s4).y, (w4));               \
    fma4(acc[2], (s4).z, (w4));               \
    fma4(acc[3], (s4).w, (w4));

// transposed store: value v (4 cols c0..c0+3) of agent a into [row=c][agent] array at base B
#define STT(B, c0, a, v)                          \
    lds[(B) + ta((c0) + 0, (a))] = (v).x;         \
    lds[(B) + ta((c0) + 1, (a))] = (v).y;         \
    lds[(B) + ta((c0) + 2, (a))] = (v).z;         \
    lds[(B) + ta((c0) + 3, (a))] = (v).w;

__device__ __forceinline__ float4 addrelu4(float4 v, float4 b) {
    return make_float4(fmaxf(v.x + b.x, 0.f), fmaxf(v.y + b.y, 0.f),
                       fmaxf(v.z + b.z, 0.f), fmaxf(v.w + b.w, 0.f));
}
__device__ __forceinline__ float4 tanh4(float4 v) {
    return make_float4(tanhf(v.x), tanhf(v.y), tanhf(v.z), tanhf(v.w));
}
__device__ __forceinline__ float4 lrelu4(float4 v) {
    return make_float4(fmaxf(v.x, 0.01f * v.x), fmaxf(v.y, 0.01f * v.y),
                       fmaxf(v.z, 0.01f * v.z), fmaxf(v.w, 0.01f * v.w));
}

__global__ void prep_weights(const float* __restrict__ Wobs, const float* __restrict__ Woa,
                             const float* __restrict__ Wk,   const float* __restrict__ Wq,
                             const float* __restrict__ Wav,  const float* __restrict__ Wf1,
                             const float* __restrict__ Wf2,  float* __restrict__ ws) {
    int tid = blockIdx.x * 256 + threadIdx.x;
    if (tid >= WS_FLOATS) return;
    if (tid < 8192)       { int r = tid;          int k = r >> 6, o = r & 63; ws[tid] = Wobs[o * 128 + k]; }
    else if (tid < 17408) { int r = tid - 8192;   int k = r >> 6, o = r & 63; ws[tid] = Woa[o * 144 + k]; }
    else if (tid < 21504) { int r = tid - 17408;  int k = r >> 6, o = r & 63; ws[tid] = Wk[o * 64 + k]; }
    else if (tid < 25600) { int r = tid - 21504;  int k = r >> 6, o = r & 63; ws[tid] = Wq[o * 64 + k]; }
    else if (tid < 29696) { int r = tid - 25600;  int k = r >> 6, o = r & 63; ws[tid] = Wav[o * 64 + k]; }
    else if (tid < 33792) { int r = tid - 29696;  int k = r >> 6, o = r & 63; ws[tid] = Wf1[o * 64 + k]; }
    else                  { int r = tid - 33792;  int k = r >> 4, p = r & 15; ws[tid] = Wf2[p * 64 + k]; }
}

__global__ void __launch_bounds__(128)
critic_main(const float* __restrict__ states, const float* __restrict__ policies,
            const float* __restrict__ actions, const float* __restrict__ b_obs,
            const float* __restrict__ b_oa, const float* __restrict__ ws,
            float* __restrict__ out_value,   // [B,32,16]
            float* __restrict__ out_weight)  // [B,32,32]
{
    __shared__ float lds[LDSF];
    const int b = blockIdx.x;
    const int t = threadIdx.x;           // 128 threads = 2 waves
    const int o4 = t & 15;               // output col-quad (cols o4*4..+3)
    const int g = t >> 4;                // agent-quad 0..7 (agents g*4..+3)

    // ---------------- stage activations (transposed+swizzled) ----------------
    {
        const float4* src = (const float4*)(states + (size_t)b * 4096);
        #pragma unroll
        for (int r = 0; r < 8; ++r) {
            int e4 = t + r * 128;               // 1024 float4
            int a = e4 >> 5, k0 = (e4 & 31) * 4;
            float4 v = src[e4];
            lds[R1 + ta(k0 + 0, a)] = v.x;
            lds[R1 + ta(k0 + 1, a)] = v.y;
            lds[R1 + ta(k0 + 2, a)] = v.z;
            lds[R1 + ta(k0 + 3, a)] = v.w;
        }
        #pragma unroll
        for (int r = 0; r < 4; ++r) {
            int e = t + r * 128;                // 512 floats each
            int a = e >> 4, k = e & 15;
            lds[R2 + ta(k, a)]       = actions[(size_t)b * 512 + e];
            lds[R2 + 512 + ta(k, a)] = policies[(size_t)b * 512 + e];
        }
    }
    __syncthreads();

    // ------------- phase A: E = relu(S@WobsT+b), EA/EP = relu(S@WoaT[:128]+tail+b) -------------
    {
        float4 accE[4], accSP[4];
        #pragma unroll
        for (int j = 0; j < 4; ++j) {
            accE[j] = make_float4(0.f, 0.f, 0.f, 0.f);
            accSP[j] = make_float4(0.f, 0.f, 0.f, 0.f);
        }
        const float* WO = ws + WOBS_T + o4 * 4;
        const float* WA = ws + WOA_T + o4 * 4;
        #pragma unroll 8
        for (int k = 0; k < 128; ++k) {
            float4 s4 = *(const float4*)&lds[R1 + tq(k, g)];
            float4 wo = *(const float4*)&WO[k * 64];
            float4 wa = *(const float4*)&WA[k * 64];
            FMA_QUAD(accE, s4, wo);
            FMA_QUAD(accSP, s4, wa);
        }
        float4 accEA[4], accEP[4];
        #pragma unroll
        for (int j = 0; j < 4; ++j) { accEA[j] = accSP[j]; accEP[j] = accSP[j]; }
        #pragma unroll
        for (int k = 0; k < 16; ++k) {
            float4 a4 = *(const float4*)&lds[R2 + tq(k, g)];
            float4 p4 = *(const float4*)&lds[R2 + 512 + tq(k, g)];
            float4 w = *(const float4*)&WA[(128 + k) * 64];
            FMA_QUAD(accEA, a4, w);
            FMA_QUAD(accEP, p4, w);
        }
        float4 bo = *(const float4*)&b_obs[o4 * 4];
        float4 ba = *(const float4*)&b_oa[o4 * 4];
        #pragma unroll
        for (int j = 0; j < 4; ++j) {
            int a = g * 4 + j;
            float4 e = addrelu4(accE[j], bo);
            float4 ea = addrelu4(accEA[j], ba);
            float4 ep = addrelu4(accEP[j], ba);
            STT(R3, o4 * 4, a, e);
            STT(R2 + 1024, o4 * 4, a, ea);
            STT(R2 + 3072, o4 * 4, a, ep);
        }
    }
    __syncthreads();

    // ------------- phase B: K = E@WkT, Q = E@WqT (stored transposed) -------------
    {
        float4 aK[4], aQ[4];
        #pragma unroll
        for (int j = 0; j < 4; ++j) {
            aK[j] = make_float4(0.f, 0.f, 0.f, 0.f);
            aQ[j] = make_float4(0.f, 0.f, 0.f, 0.f);
        }
        const float* Wk = ws + WK_T + o4 * 4;
        const float* Wq = ws + WQ_T + o4 * 4;
        #pragma unroll 8
        for (int k = 0; k < 64; ++k) {
            float4 s4 = *(const float4*)&lds[R3 + tq(k, g)];
            float4 wk = *(const float4*)&Wk[k * 64];
            float4 wq = *(const float4*)&Wq[k * 64];
            FMA_QUAD(aK, s4, wk);
            FMA_QUAD(aQ, s4, wq);
        }
        #pragma unroll
        for (int j = 0; j < 4; ++j) {
            int a = g * 4 + j;
            STT(R1, o4 * 4, a, aK[j]);
            STT(R1 + 2048, o4 * 4, a, aQ[j]);
        }
    }
    __syncthreads();

    // ------------- score + softmax: w[j][i] = softmax_i(q_i . k_j / 8) -------------
    {
        int i4s = t & 7;       // i col-quad 0..7
        int jq = t >> 3;       // 0..15 -> rows j0=2jq, j1=2jq+1
        int j0 = jq * 2, j1 = j0 + 1;
        float4 a0 = make_float4(0.f, 0.f, 0.f, 0.f);
        float4 a1 = make_float4(0.f, 0.f, 0.f, 0.f);
        #pragma unroll 8
        for (int d = 0; d < 64; ++d) {
            float4 q4 = *(const float4*)&lds[R1 + 2048 + tq(d, i4s)];
            int kb = R1 + tq(d, jq >> 1) + ((jq & 1) * 2);
            float k0v = lds[kb], k1v = lds[kb + 1];
            fma4(a0, k0v, q4);
            fma4(a1, k1v, q4);
        }
        const float sc = 0.125f;
        a0.x *= sc; a0.y *= sc; a0.z *= sc; a0.w *= sc;
        a1.x *= sc; a1.y *= sc; a1.z *= sc; a1.w *= sc;
        float m0 = fmaxf(fmaxf(a0.x, a0.y), fmaxf(a0.z, a0.w));
        float m1 = fmaxf(fmaxf(a1.x, a1.y), fmaxf(a1.z, a1.w));
        #pragma unroll
        for (int off = 4; off; off >>= 1) {
            m0 = fmaxf(m0, __shfl_xor(m0, off, 8));
            m1 = fmaxf(m1, __shfl_xor(m1, off, 8));
        }
        a0.x = __expf(a0.x - m0); a0.y = __expf(a0.y - m0);
        a0.z = __expf(a0.z - m0); a0.w = __expf(a0.w - m0);
        a1.x = __expf(a1.x - m1); a1.y = __expf(a1.y - m1);
        a1.z = __expf(a1.z - m1); a1.w = __expf(a1.w - m1);
        float s0 = a0.x + a0.y + a0.z + a0.w;
        float s1 = a1.x + a1.y + a1.z + a1.w;
        #pragma unroll
        for (int off = 4; off; off >>= 1) {
            s0 += __shfl_xor(s0, off, 8);
            s1 += __shfl_xor(s1, off, 8);
        }
        float i0 = 1.0f / s0, i1 = 1.0f / s1;
        a0.x *= i0; a0.y *= i0; a0.z *= i0; a0.w *= i0;
        a1.x *= i1; a1.y *= i1; a1.z *= i1; a1.w *= i1;
        float* wout = out_weight + (size_t)b * 1024;
        *(float4*)&wout[j0 * 32 + i4s * 4] = a0;
        *(float4*)&wout[j1 * 32 + i4s * 4] = a1;
        STT(R4, i4s * 4, j0, a0);   // WT[i][j] = w[j][i]
        STT(R4, i4s * 4, j1, a1);
    }
    __syncthreads();

    // ------------- phase C: AA/AP = tanh(EA/EP @ WavT), stored natural [agent][64] -------------
    {
        float4 aA[4], aP[4];
        #pragma unroll
        for (int j = 0; j < 4; ++j) {
            aA[j] = make_float4(0.f, 0.f, 0.f, 0.f);
            aP[j] = make_float4(0.f, 0.f, 0.f, 0.f);
        }
        const float* Wv = ws + WAV_T + o4 * 4;
        #pragma unroll 8
        for (int k = 0; k < 64; ++k) {
            float4 e4 = *(const float4*)&lds[R2 + 1024 + tq(k, g)];
            float4 p4 = *(const float4*)&lds[R2 + 3072 + tq(k, g)];
            float4 wv = *(const float4*)&Wv[k * 64];
            FMA_QUAD(aA, e4, wv);
            FMA_QUAD(aP, p4, wv);
        }
        #pragma unroll
        for (int j = 0; j < 4; ++j) {
            int a = g * 4 + j;
            float4 va = tanh4(aA[j]);
            float4 vp = tanh4(aP[j]);
            *(float4*)&lds[R1 + a * 64 + o4 * 4] = va;
            *(float4*)&lds[R1 + 2048 + a * 64 + o4 * 4] = vp;
        }
    }
    __syncthreads();

    // ------------- phase D: NF[j] = (1/32)(sum_i w[j,i] AA[i] + w[j,j](AP[j]-AA[j])) -------------
    {
        float4 acc[4];
        #pragma unroll
        for (int j = 0; j < 4; ++j) acc[j] = make_float4(0.f, 0.f, 0.f, 0.f);
        #pragma unroll 8
        for (int i = 0; i < 32; ++i) {
            float4 s4 = *(const float4*)&lds[R4 + tq(i, g)];   // w[g*4+j][i]
            float4 av = *(const float4*)&lds[R1 + i * 64 + o4 * 4];
            FMA_QUAD(acc, s4, av);
        }
        #pragma unroll
        for (int j = 0; j < 4; ++j) {
            int a = g * 4 + j;
            float wd = lds[R4 + ta(a, a)];
            float4 aa = *(const float4*)&lds[R1 + a * 64 + o4 * 4];
            float4 ap = *(const float4*)&lds[R1 + 2048 + a * 64 + o4 * 4];
            acc[j].x = (acc[j].x + wd * (ap.x - aa.x)) * 0.03125f;
            acc[j].y = (acc[j].y + wd * (ap.y - aa.y)) * 0.03125f;
            acc[j].z = (acc[j].z + wd * (ap.z - aa.z)) * 0.03125f;
            acc[j].w = (acc[j].w + wd * (ap.w - aa.w)) * 0.03125f;
            STT(R3, o4 * 4, a, acc[j]);   // NF_T
        }
    }
    __syncthreads();

    // ------------- phase E: H = leaky_relu(NF @ Wf1T), stored transposed -------------
    {
        float4 acc[4];
        #pragma unroll
        for (int j = 0; j < 4; ++j) acc[j] = make_float4(0.f, 0.f, 0.f, 0.f);
        const float* W1 = ws + WF1_T + o4 * 4;
        #pragma unroll 8
        for (int k = 0; k < 64; ++k) {
            float4 s4 = *(const float4*)&lds[R3 + tq(k, g)];
            float4 w = *(const float4*)&W1[k * 64];
            FMA_QUAD(acc, s4, w);
        }
        #pragma unroll
        for (int j = 0; j < 4; ++j) {
            float4 h = lrelu4(acc[j]);
            STT(R1, o4 * 4, g * 4 + j, h);   // H_T[64][32]
        }
    }
    __syncthreads();

    // ------------- phase F: value = H @ Wf2T -------------
    {
        int a = t >> 2, p4 = t & 3;
        float4 acc = make_float4(0.f, 0.f, 0.f, 0.f);
        const float* W2 = ws + WF2_T + p4 * 4;
        #pragma unroll 8
        for (int k = 0; k < 64; ++k) {
            float hv = lds[R1 + ta(k, a)];
            float4 w = *(const float4*)&W2[k * 16];
            fma4(acc, hv, w);
        }
        *(float4*)&out_value[(size_t)b * 512 + a * 16 + p4 * 4] = acc;
    }
}

extern "C" void kernel_launch(void* const* d_in, const int* in_sizes, int n_in,
                              void* d_out, int out_size, void* d_ws, size_t ws_size,
                              hipStream_t stream) {
    const float* states   = (const float*)d_in[0];
    const float* policies = (const float*)d_in[1];
    const float* actions  = (const float*)d_in[2];
    const float* W_obs    = (const float*)d_in[3];
    const float* b_obs    = (const float*)d_in[4];
    const float* W_oa     = (const float*)d_in[5];
    const float* b_oa     = (const float*)d_in[6];
    const float* W_key    = (const float*)d_in[7];
    const float* W_query  = (const float*)d_in[8];
    const float* W_av     = (const float*)d_in[9];
    const float* W_f1     = (const float*)d_in[10];
    const float* W_f2     = (const float*)d_in[11];

    float* ws = (float*)d_ws;
    float* out_value  = (float*)d_out;                 // [512,32,16]
    float* out_weight = (float*)d_out + NB * 32 * 16;  // [512,32,32]

    prep_weights<<<(WS_FLOATS + 255) / 256, 256, 0, stream>>>(
        W_obs, W_oa, W_key, W_query, W_av, W_f1, W_f2, ws);
    critic_main<<<NB, 128, 0, stream>>>(states, policies, actions,
                                        b_obs, b_oa, ws, out_value, out_weight);
}

// Round 3
// 49.626 us; speedup vs baseline: 3.3446x; 1.0206x over previous
//
#include <hip/hip_runtime.h>

#define NB 512

// ---- d_ws layout (floats): transposed weights W^T[k][o] ----
#define WOBS_T 0        // [128][64]
#define WOA_T  8192     // [144][64]
#define WK_T   17408    // [64][64]
#define WQ_T   21504    // [64][64]
#define WAV_T  25600    // [64][64]
#define WF1_T  29696    // [64][64]
#define WF2_T  33792    // [64][16]
#define WS_FLOATS 34816 // 139264 bytes

// ---- LDS arena (floats), total 12288 = 48 KiB ----
// R1 [4096]: S_T[128][32] -> K_T[64][32]@R1, Q_T@R1+2048 -> AA[32][64]@R1, AP@R1+2048 -> H_T[64][32]@R1
// R2 [5120]: AT[16][32]@R2, PT@R2+512, EA_T[64][32]@R2+1024, EP_T@R2+3072
// R3 [2048]: E_T[64][32] -> NF_T[64][32]
// R4 [1024]: WT[32][32] (attention weights, transposed: WT[i][j] = w[j][i])
#define R1 0
#define R2 4096
#define R3 9216
#define R4 11264
#define LDSF 12288

// swizzled [row][32-agent] addressing: agent-quad XOR'd with (row>>2)&7
__device__ __forceinline__ int tq(int r, int q) {
    return r * 32 + (((q ^ (r >> 2)) & 7) << 2);
}
__device__ __forceinline__ int ta(int r, int a) {
    return tq(r, a >> 2) + (a & 3);
}
// agent-pair addressing (pair gp -> agents gp*2, gp*2+1), float2-aligned
__device__ __forceinline__ int tp(int r, int gp) {
    return tq(r, gp >> 1) + ((gp & 1) * 2);
}

__device__ __forceinline__ void fma4(float4& a, float s, float4 w) {
    a.x = fmaf(s, w.x, a.x);
    a.y = fmaf(s, w.y, a.y);
    a.z = fmaf(s, w.z, a.z);
    a.w = fmaf(s, w.w, a.w);
}

#define FMA_PAIR(acc, s2, w4)                 \
    fma4(acc[0], (s2).x, (w4));               \
    fma4(acc[1], (s2).y, (w4));

// transposed store: value v (4 rows c0..c0+3) of agent a into [row][agent] array at base B
#define STT(B, c0, a, v)                          \
    lds[(B) + ta((c0) + 0, (a))] = (v).x;         \
    lds[(B) + ta((c0) + 1, (a))] = (v).y;         \
    lds[(B) + ta((c0) + 2, (a))] = (v).z;         \
    lds[(B) + ta((c0) + 3, (a))] = (v).w;

__device__ __forceinline__ float4 addrelu4(float4 v, float4 b) {
    return make_float4(fmaxf(v.x + b.x, 0.f), fmaxf(v.y + b.y, 0.f),
                       fmaxf(v.z + b.z, 0.f), fmaxf(v.w + b.w, 0.f));
}
__device__ __forceinline__ float fast_tanh(float x) {
    float xc = fminf(fmaxf(x, -9.0f), 9.0f);
    float e = __expf(2.0f * xc);
    return (e - 1.0f) * __builtin_amdgcn_rcpf(e + 1.0f);
}
__device__ __forceinline__ float4 tanh4(float4 v) {
    return make_float4(fast_tanh(v.x), fast_tanh(v.y), fast_tanh(v.z), fast_tanh(v.w));
}
__device__ __forceinline__ float4 lrelu4(float4 v) {
    return make_float4(fmaxf(v.x, 0.01f * v.x), fmaxf(v.y, 0.01f * v.y),
                       fmaxf(v.z, 0.01f * v.z), fmaxf(v.w, 0.01f * v.w));
}

__global__ void prep_weights(const float* __restrict__ Wobs, const float* __restrict__ Woa,
                             const float* __restrict__ Wk,   const float* __restrict__ Wq,
                             const float* __restrict__ Wav,  const float* __restrict__ Wf1,
                             const float* __restrict__ Wf2,  float* __restrict__ ws) {
    int tid = blockIdx.x * 256 + threadIdx.x;
    if (tid >= WS_FLOATS) return;
    if (tid < 8192)       { int r = tid;          int k = r >> 6, o = r & 63; ws[tid] = Wobs[o * 128 + k]; }
    else if (tid < 17408) { int r = tid - 8192;   int k = r >> 6, o = r & 63; ws[tid] = Woa[o * 144 + k]; }
    else if (tid < 21504) { int r = tid - 17408;  int k = r >> 6, o = r & 63; ws[tid] = Wk[o * 64 + k]; }
    else if (tid < 25600) { int r = tid - 21504;  int k = r >> 6, o = r & 63; ws[tid] = Wq[o * 64 + k]; }
    else if (tid < 29696) { int r = tid - 25600;  int k = r >> 6, o = r & 63; ws[tid] = Wav[o * 64 + k]; }
    else if (tid < 33792) { int r = tid - 29696;  int k = r >> 6, o = r & 63; ws[tid] = Wf1[o * 64 + k]; }
    else                  { int r = tid - 33792;  int k = r >> 4, p = r & 15; ws[tid] = Wf2[p * 64 + k]; }
}

__global__ void __launch_bounds__(256)
critic_main(const float* __restrict__ states, const float* __restrict__ policies,
            const float* __restrict__ actions, const float* __restrict__ b_obs,
            const float* __restrict__ b_oa, const float* __restrict__ ws,
            float* __restrict__ out_value,   // [B,32,16]
            float* __restrict__ out_weight)  // [B,32,32]
{
    __shared__ float lds[LDSF];
    const int b = blockIdx.x;
    const int t = threadIdx.x;           // 256 threads = 4 waves
    const int o4 = t & 15;               // output col-quad (cols o4*4..+3)
    const int gp = t >> 4;               // agent-pair 0..15 (agents gp*2, gp*2+1)
    const int a0 = gp * 2, a1 = a0 + 1;

    // ---------------- stage activations (transposed+swizzled) ----------------
    {
        const float4* src = (const float4*)(states + (size_t)b * 4096);
        #pragma unroll
        for (int r = 0; r < 4; ++r) {
            int e4 = t + r * 256;               // 1024 float4
            int a = e4 >> 5, k0 = (e4 & 31) * 4;
            float4 v = src[e4];
            lds[R1 + ta(k0 + 0, a)] = v.x;
            lds[R1 + ta(k0 + 1, a)] = v.y;
            lds[R1 + ta(k0 + 2, a)] = v.z;
            lds[R1 + ta(k0 + 3, a)] = v.w;
        }
        #pragma unroll
        for (int r = 0; r < 2; ++r) {
            int e = t + r * 256;                // 512 floats each
            int a = e >> 4, k = e & 15;
            lds[R2 + ta(k, a)]       = actions[(size_t)b * 512 + e];
            lds[R2 + 512 + ta(k, a)] = policies[(size_t)b * 512 + e];
        }
    }
    __syncthreads();

    // ------------- phase A: E = relu(S@WobsT+b), EA/EP = relu(S@WoaT[:128]+tail+b) -------------
    {
        float4 accE[2], accSP[2];
        #pragma unroll
        for (int j = 0; j < 2; ++j) {
            accE[j] = make_float4(0.f, 0.f, 0.f, 0.f);
            accSP[j] = make_float4(0.f, 0.f, 0.f, 0.f);
        }
        const float* WO = ws + WOBS_T + o4 * 4;
        const float* WA = ws + WOA_T + o4 * 4;
        #pragma unroll 8
        for (int k = 0; k < 128; ++k) {
            float2 s2 = *(const float2*)&lds[R1 + tp(k, gp)];
            float4 wo = *(const float4*)&WO[k * 64];
            float4 wa = *(const float4*)&WA[k * 64];
            FMA_PAIR(accE, s2, wo);
            FMA_PAIR(accSP, s2, wa);
        }
        float4 accEA[2], accEP[2];
        #pragma unroll
        for (int j = 0; j < 2; ++j) { accEA[j] = accSP[j]; accEP[j] = accSP[j]; }
        #pragma unroll
        for (int k = 0; k < 16; ++k) {
            float2 a2 = *(const float2*)&lds[R2 + tp(k, gp)];
            float2 p2 = *(const float2*)&lds[R2 + 512 + tp(k, gp)];
            float4 w = *(const float4*)&WA[(128 + k) * 64];
            FMA_PAIR(accEA, a2, w);
            FMA_PAIR(accEP, p2, w);
        }
        float4 bo = *(const float4*)&b_obs[o4 * 4];
        float4 ba = *(const float4*)&b_oa[o4 * 4];
        float4 e0 = addrelu4(accE[0], bo),  e1 = addrelu4(accE[1], bo);
        float4 ea0 = addrelu4(accEA[0], ba), ea1 = addrelu4(accEA[1], ba);
        float4 ep0 = addrelu4(accEP[0], ba), ep1 = addrelu4(accEP[1], ba);
        STT(R3, o4 * 4, a0, e0);  STT(R3, o4 * 4, a1, e1);
        STT(R2 + 1024, o4 * 4, a0, ea0);  STT(R2 + 1024, o4 * 4, a1, ea1);
        STT(R2 + 3072, o4 * 4, a0, ep0);  STT(R2 + 3072, o4 * 4, a1, ep1);
    }
    __syncthreads();

    // ------------- phase B: K = E@WkT, Q = E@WqT (stored transposed) -------------
    {
        float4 aK[2], aQ[2];
        #pragma unroll
        for (int j = 0; j < 2; ++j) {
            aK[j] = make_float4(0.f, 0.f, 0.f, 0.f);
            aQ[j] = make_float4(0.f, 0.f, 0.f, 0.f);
        }
        const float* Wk = ws + WK_T + o4 * 4;
        const float* Wq = ws + WQ_T + o4 * 4;
        #pragma unroll 8
        for (int k = 0; k < 64; ++k) {
            float2 s2 = *(const float2*)&lds[R3 + tp(k, gp)];
            float4 wk = *(const float4*)&Wk[k * 64];
            float4 wq = *(const float4*)&Wq[k * 64];
            FMA_PAIR(aK, s2, wk);
            FMA_PAIR(aQ, s2, wq);
        }
        STT(R1, o4 * 4, a0, aK[0]);  STT(R1, o4 * 4, a1, aK[1]);
        STT(R1 + 2048, o4 * 4, a0, aQ[0]);  STT(R1 + 2048, o4 * 4, a1, aQ[1]);
    }
    __syncthreads();

    // ------------- score + softmax: w[j][i] = softmax_i(q_i . k_j / 8) -------------
    {
        int i4s = t & 7;       // i col-quad 0..7
        int j = t >> 3;        // row 0..31
        float4 a = make_float4(0.f, 0.f, 0.f, 0.f);
        #pragma unroll 8
        for (int d = 0; d < 64; ++d) {
            float4 q4 = *(const float4*)&lds[R1 + 2048 + tq(d, i4s)];
            float kv = lds[R1 + ta(d, j)];
            fma4(a, kv, q4);
        }
        const float sc = 0.125f;
        a.x *= sc; a.y *= sc; a.z *= sc; a.w *= sc;
        float m = fmaxf(fmaxf(a.x, a.y), fmaxf(a.z, a.w));
        #pragma unroll
        for (int off = 4; off; off >>= 1)
            m = fmaxf(m, __shfl_xor(m, off, 8));
        a.x = __expf(a.x - m); a.y = __expf(a.y - m);
        a.z = __expf(a.z - m); a.w = __expf(a.w - m);
        float s = a.x + a.y + a.z + a.w;
        #pragma unroll
        for (int off = 4; off; off >>= 1)
            s += __shfl_xor(s, off, 8);
        float inv = 1.0f / s;
        a.x *= inv; a.y *= inv; a.z *= inv; a.w *= inv;
        float* wout = out_weight + (size_t)b * 1024;
        *(float4*)&wout[j * 32 + i4s * 4] = a;
        STT(R4, i4s * 4, j, a);   // WT[i][j] = w[j][i]
    }
    __syncthreads();

    // ------------- phase C: AA/AP = tanh(EA/EP @ WavT), stored natural [agent][64] -------------
    {
        float4 aA[2], aP[2];
        #pragma unroll
        for (int j = 0; j < 2; ++j) {
            aA[j] = make_float4(0.f, 0.f, 0.f, 0.f);
            aP[j] = make_float4(0.f, 0.f, 0.f, 0.f);
        }
        const float* Wv = ws + WAV_T + o4 * 4;
        #pragma unroll 8
        for (int k = 0; k < 64; ++k) {
            float2 e2 = *(const float2*)&lds[R2 + 1024 + tp(k, gp)];
            float2 p2 = *(const float2*)&lds[R2 + 3072 + tp(k, gp)];
            float4 wv = *(const float4*)&Wv[k * 64];
            FMA_PAIR(aA, e2, wv);
            FMA_PAIR(aP, p2, wv);
        }
        *(float4*)&lds[R1 + a0 * 64 + o4 * 4] = tanh4(aA[0]);
        *(float4*)&lds[R1 + a1 * 64 + o4 * 4] = tanh4(aA[1]);
        *(float4*)&lds[R1 + 2048 + a0 * 64 + o4 * 4] = tanh4(aP[0]);
        *(float4*)&lds[R1 + 2048 + a1 * 64 + o4 * 4] = tanh4(aP[1]);
    }
    __syncthreads();

    // ------------- phase D: NF[j] = (1/32)(sum_i w[j,i] AA[i] + w[j,j](AP[j]-AA[j])) -------------
    {
        float4 acc[2];
        acc[0] = make_float4(0.f, 0.f, 0.f, 0.f);
        acc[1] = make_float4(0.f, 0.f, 0.f, 0.f);
        #pragma unroll 8
        for (int i = 0; i < 32; ++i) {
            float2 w2 = *(const float2*)&lds[R4 + tp(i, gp)];   // w[a0][i], w[a1][i]
            float4 av = *(const float4*)&lds[R1 + i * 64 + o4 * 4];
            FMA_PAIR(acc, w2, av);
        }
        #pragma unroll
        for (int j = 0; j < 2; ++j) {
            int a = a0 + j;
            float wd = lds[R4 + ta(a, a)];
            float4 aa = *(const float4*)&lds[R1 + a * 64 + o4 * 4];
            float4 ap = *(const float4*)&lds[R1 + 2048 + a * 64 + o4 * 4];
            acc[j].x = (acc[j].x + wd * (ap.x - aa.x)) * 0.03125f;
            acc[j].y = (acc[j].y + wd * (ap.y - aa.y)) * 0.03125f;
            acc[j].z = (acc[j].z + wd * (ap.z - aa.z)) * 0.03125f;
            acc[j].w = (acc[j].w + wd * (ap.w - aa.w)) * 0.03125f;
        }
        __syncthreads();   // AA/AP fully read; safe to overwrite R3? (R3 = NF dest, E dead)
        STT(R3, o4 * 4, a0, acc[0]);   // NF_T
        STT(R3, o4 * 4, a1, acc[1]);
    }
    __syncthreads();

    // ------------- phase E: H = leaky_relu(NF @ Wf1T), stored transposed -------------
    {
        float4 acc[2];
        acc[0] = make_float4(0.f, 0.f, 0.f, 0.f);
        acc[1] = make_float4(0.f, 0.f, 0.f, 0.f);
        const float* W1 = ws + WF1_T + o4 * 4;
        #pragma unroll 8
        for (int k = 0; k < 64; ++k) {
            float2 s2 = *(const float2*)&lds[R3 + tp(k, gp)];
            float4 w = *(const float4*)&W1[k * 64];
            FMA_PAIR(acc, s2, w);
        }
        float4 h0 = lrelu4(acc[0]), h1 = lrelu4(acc[1]);
        STT(R1, o4 * 4, a0, h0);   // H_T[64][32]
        STT(R1, o4 * 4, a1, h1);
    }
    __syncthreads();

    // ------------- phase F: value = H @ Wf2T -------------
    {
        int a = t >> 3, p2 = t & 7;
        float2 acc = make_float2(0.f, 0.f);
        const float* W2 = ws + WF2_T + p2 * 2;
        #pragma unroll 8
        for (int k = 0; k < 64; ++k) {
            float hv = lds[R1 + ta(k, a)];
            float2 w = *(const float2*)&W2[k * 16];
            acc.x = fmaf(hv, w.x, acc.x);
            acc.y = fmaf(hv, w.y, acc.y);
        }
        *(float2*)&out_value[(size_t)b * 512 + a * 16 + p2 * 2] = acc;
    }
}

extern "C" void kernel_launch(void* const* d_in, const int* in_sizes, int n_in,
                              void* d_out, int out_size, void* d_ws, size_t ws_size,
                              hipStream_t stream) {
    const float* states   = (const float*)d_in[0];
    const float* policies = (const float*)d_in[1];
    const float* actions  = (const float*)d_in[2];
    const float* W_obs    = (const float*)d_in[3];
    const float* b_obs    = (const float*)d_in[4];
    const float* W_oa     = (const float*)d_in[5];
    const float* b_oa     = (const float*)d_in[6];
    const float* W_key    = (const float*)d_in[7];
    const float* W_query  = (const float*)d_in[8];
    const float* W_av     = (const float*)d_in[9];
    const float* W_f1     = (const float*)d_in[10];
    const float* W_f2     = (const float*)d_in[11];

    float* ws = (float*)d_ws;
    float* out_value  = (float*)d_out;                 // [512,32,16]
    float* out_weight = (float*)d_out + NB * 32 * 16;  // [512,32,32]

    prep_weights<<<(WS_FLOATS + 255) / 256, 256, 0, stream>>>(
        W_obs, W_oa, W_key, W_query, W_av, W_f1, W_f2, ws);
    critic_main<<<NB, 256, 0, stream>>>(states, policies, actions,
                                        b_obs, b_oa, ws, out_value, out_weight);
}